// Round 1
// baseline (2157.701 us; speedup 1.0000x reference)
//
#include <hip/hip_runtime.h>

// Problem constants
#define N_   16
#define CI_  32
#define CO_  64
#define DI   16
#define HI   32
#define WI   32
// ConvT: k=5, s=2, p=2 -> conv out (31,63,63); fused maxpool k=6 s=6 -> (5,10,10)

// Transpose weights: src [ci][co][kd][kh][kw] -> dst [ci][kd][kh][kw][co]
// so that for fixed (ci,kd,kh,kw) the 64 lanes (= co) read 256 contiguous bytes.
__global__ void wt_transpose_kernel(const float* __restrict__ w, float* __restrict__ wT) {
    int t = blockIdx.x * blockDim.x + threadIdx.x;
    if (t >= CI_ * 125 * CO_) return;
    int co = t & 63;
    int q  = t >> 6;            // (((ci*5+kd)*5+kh)*5+kw)
    int kw = q % 5;
    int kh = (q / 5) % 5;
    int kd = (q / 25) % 5;
    int ci = q / 125;
    wT[t] = w[(ci * CO_ + co) * 125 + kd * 25 + kh * 5 + kw];
}

// One block per output scalar (n, dj, hj, wj).
// 384 threads = 6 waves; wave index = local output-d (dloc 0..5), lane = co.
__global__ __launch_bounds__(384, 3)
void fused_convt_pool_sum(const float* __restrict__ x,
                          const float* __restrict__ wT,
                          const float* __restrict__ bias,
                          float* __restrict__ out) {
    __shared__ float xs[4000];   // x patch [ci=32][id=5][ih=5][iw=5]
    __shared__ float red[384];

    const int b  = blockIdx.x;
    const int wj = b % 10;
    const int hj = (b / 10) % 10;
    const int dj = (b / 100) % 5;
    const int n  = b / 500;

    const int id0 = 3 * dj - 1;
    const int ih0 = 3 * hj - 1;
    const int iw0 = 3 * wj - 1;

    const float* xn = x + (size_t)n * (CI_ * DI * HI * WI);

    // Stage x patch (zero-pad at low edges; high edges never exceed bounds:
    // id<=15, ih/iw<=30).
    for (int e = threadIdx.x; e < 4000; e += 384) {
        int ci  = e / 125;
        int r   = e % 125;
        int idl = r / 25;
        int ihl = (r / 5) % 5;
        int iwl = r % 5;
        int id = id0 + idl, ih = ih0 + ihl, iw = iw0 + iwl;
        float v = 0.f;
        if (id >= 0 && ih >= 0 && iw >= 0)
            v = xn[((ci * DI + id) * HI + ih) * WI + iw];
        xs[e] = v;
    }
    __syncthreads();

    const int lane = threadIdx.x & 63;   // co
    const int dloc = threadIdx.x >> 6;   // 0..5, wave-uniform
    const int p    = dloc & 1;           // parity of od -> 3 or 2 d-taps
    const int mh   = dloc >> 1;          // (od>>1) - 3*dj

    float acc[6][6];
    #pragma unroll
    for (int a = 0; a < 6; ++a)
        #pragma unroll
        for (int c = 0; c < 6; ++c) acc[a][c] = 0.f;

    const int nj = 3 - p;                // wave-uniform trip count

    for (int ci = 0; ci < CI_; ++ci) {
        const float* wci = wT + ci * 8000 + lane;   // [kd][kh][kw][co]
        const float* xci = xs + ci * 125;
        #pragma unroll 1
        for (int j = 0; j < nj; ++j) {
            const int kd  = p + 2 * j;          // tap
            const int idl = mh + 2 - j;         // local input d (0..4)

            float wt[25];
            const float* wp = wci + kd * 1600;  // kd*5*5*64
            #pragma unroll
            for (int u = 0; u < 25; ++u) wt[u] = wp[u * 64];

            float xr[25];
            const float* xp = xci + idl * 25;
            #pragma unroll
            for (int u = 0; u < 25; ++u) xr[u] = xp[u];

            // 225 FMAs, all operands in registers
            #pragma unroll
            for (int hl = 0; hl < 6; ++hl) {
                const int ph = hl & 1, mhh = hl >> 1;
                #pragma unroll
                for (int jh = 0; jh < 3; ++jh) {
                    if (ph && jh == 2) continue;        // compile-time prune
                    const int kh  = ph + 2 * jh;
                    const int ihl = mhh + 2 - jh;
                    #pragma unroll
                    for (int wl = 0; wl < 6; ++wl) {
                        const int pw = wl & 1, mww = wl >> 1;
                        #pragma unroll
                        for (int jw = 0; jw < 3; ++jw) {
                            if (pw && jw == 2) continue;
                            const int kw  = pw + 2 * jw;
                            const int iwl = mww + 2 - jw;
                            acc[hl][wl] = fmaf(xr[ihl * 5 + iwl], wt[kh * 5 + kw],
                                               acc[hl][wl]);
                        }
                    }
                }
            }
        }
    }

    // per-thread max over its 6x6 (h,w) tile
    float m = acc[0][0];
    #pragma unroll
    for (int a = 0; a < 6; ++a)
        #pragma unroll
        for (int c = 0; c < 6; ++c) m = fmaxf(m, acc[a][c]);

    red[dloc * 64 + lane] = m;
    __syncthreads();

    if (dloc == 0) {
        float v = red[lane];
        #pragma unroll
        for (int k = 1; k < 6; ++k) v = fmaxf(v, red[k * 64 + lane]);
        v += bias[lane];
        // sum across the 64 co lanes
        for (int off = 32; off > 0; off >>= 1)
            v += __shfl_down(v, off, 64);
        if (lane == 0) out[b] = v;
    }
}

extern "C" void kernel_launch(void* const* d_in, const int* in_sizes, int n_in,
                              void* d_out, int out_size, void* d_ws, size_t ws_size,
                              hipStream_t stream) {
    const float* x    = (const float*)d_in[0];   // (16,32,16,32,32)
    const float* w    = (const float*)d_in[1];   // (32,64,5,5,5)
    const float* bias = (const float*)d_in[2];   // (64,)
    float*       out  = (float*)d_out;           // (16,1,5,10,10) = 8000
    float*       wT   = (float*)d_ws;            // 256000 floats = 1 MB

    // 1) weight transpose into workspace (re-done every call; ws is re-poisoned)
    {
        int total = CI_ * 125 * CO_;             // 256000
        wt_transpose_kernel<<<(total + 255) / 256, 256, 0, stream>>>(w, wT);
    }
    // 2) fused convT + maxpool6 + bias + channel-sum
    {
        dim3 grid(N_ * 5 * 10 * 10);             // 8000 blocks
        dim3 block(384);
        fused_convt_pool_sum<<<grid, block, 0, stream>>>(x, wT, bias, out);
    }
}

// Round 2
// 331.744 us; speedup vs baseline: 6.5041x; 6.5041x over previous
//
#include <hip/hip_runtime.h>

typedef short v8s __attribute__((ext_vector_type(8)));
typedef float v4f __attribute__((ext_vector_type(4)));

#define N_  16
#define CI_ 32
#define CO_ 64
#define DI  16
#define HI  32
#define WI  32

__device__ __forceinline__ unsigned short f2bf(float f) {
    unsigned int u = __float_as_uint(f);
    unsigned int r = (u + 0x7FFFu + ((u >> 16) & 1u)) >> 16;
    return (unsigned short)r;
}

// Build w_t[class][co][k] bf16, k = tap*32 + ci, tap = (jd*nh+jh)*nw+jw.
// Class r = rd*4+rh*2+rw; kd = rd+2jd etc. Offsets O64[r] in halves.
__global__ void wprep(const float* __restrict__ w, unsigned short* __restrict__ wt) {
    const int r = blockIdx.y;
    const int rd = r >> 2, rh = (r >> 1) & 1, rw = r & 1;
    const int nd = rd ? 2 : 3, nh = rh ? 2 : 3, nw = rw ? 2 : 3;
    const int K = nd * nh * nw * 32;
    static constexpr int O64[8] = {0, 55296, 92160, 129024, 153600, 190464, 215040, 239616};
    int t = blockIdx.x * 256 + threadIdx.x;
    if (t >= 64 * K) return;
    int co = t / K;
    int k  = t - co * K;
    int ci = k & 31;
    int tap = k >> 5;
    int jw = tap % nw;
    int jh = (tap / nw) % nh;
    int jd = tap / (nw * nh);
    int kd = rd + 2 * jd, kh = rh + 2 * jh, kw = rw + 2 * jw;
    wt[O64[r] + t] = f2bf(w[(ci * CO_ + co) * 125 + kd * 25 + kh * 5 + kw]);
}

// One block per (n, dj, hj, whalf): 5 pool outputs.
// 4 waves = (class-group pair) x (M-half). MFMA 16x16x32 bf16.
__global__ __launch_bounds__(256, 3)
void fused_main(const float* __restrict__ x, const unsigned short* __restrict__ wt,
                const float* __restrict__ bias, float* __restrict__ out) {
    __shared__ unsigned short xs[14400];  // [g4][id'5][ih'5][iw'18][c8]
    __shared__ float P[2048];             // [wave4][q4][l16][nt4][slot2]
    __shared__ float Y[320];              // [co64][wjl5]

    const int b = blockIdx.x;
    const int whalf = b & 1;
    const int hj = (b >> 1) % 10;
    const int dj = (b / 20) % 5;
    const int n  = b / 100;

    const int id0 = 3 * dj - 1, ih0 = 3 * hj - 1, iwb = 15 * whalf - 1;
    const float* xn = x + (size_t)n * (CI_ * DI * HI * WI);

    // ---- stage x patch (fp32 -> bf16, transposed to ci-fastest-by-8) ----
    for (int e = threadIdx.x; e < 14400; e += 256) {
        int ci   = e / 450;
        int rem  = e - ci * 450;
        int idp  = rem / 90;
        int rem2 = rem - idp * 90;
        int ihp  = rem2 / 18;
        int iwp  = rem2 - ihp * 18;
        int id = id0 + idp, ih = ih0 + ihp, iw = iwb + iwp;
        float v = 0.f;
        if (id >= 0 && ih >= 0 && iw >= 0)
            v = xn[((ci * DI + id) * HI + ih) * WI + iw];
        xs[(ci >> 3) * 3600 + idp * 720 + ihp * 144 + iwp * 8 + (ci & 7)] = f2bf(v);
    }
    __syncthreads();

    const int lane = threadIdx.x & 63;
    const int wv   = threadIdx.x >> 6;
    const int l = lane & 15, q = lane >> 4;
    const int wp2 = wv >> 1;   // class group
    const int wp  = wv & 1;    // M split within pair

    // lane part of A address (+ constant 1728 = (2*720 + 2*144))
    const int laneA = q * 3600 + (l + 2) * 8 + 1728;

    static constexpr int Gtab[2][4] = {{0, 3, 5, 6}, {1, 2, 4, 7}};
    static constexpr int tapsT[8] = {27, 18, 18, 12, 18, 12, 12, 8};
    static constexpr int KT[8]    = {864, 576, 576, 384, 576, 384, 384, 256};
    static constexpr int O64[8]   = {0, 55296, 92160, 129024, 153600, 190464, 215040, 239616};
    static constexpr int nwT[8]   = {3, 2, 3, 2, 3, 2, 3, 2};
    static constexpr int nhT[8]   = {3, 3, 2, 2, 3, 3, 2, 2};

    float pmax[4][2];
    #pragma unroll
    for (int nt = 0; nt < 4; ++nt) { pmax[nt][0] = -INFINITY; pmax[nt][1] = -INFINITY; }
    const int wjA = (4 * q) / 3;  // pool cell of this quad's first row

    for (int c4 = 0; c4 < 4; ++c4) {
        const int r = Gtab[wp2][c4];
        const int taps = tapsT[r], K = KT[r], nw = nwT[r], nh = nhT[r];
        const int par = (wp + c4) & 1;       // row parity handled by this wave
        const int T = par ? 4 : 5;           // tiles (rows) this class
        int odl[5], ohl[5];
        #pragma unroll
        for (int t = 0; t < 5; ++t) {
            int row = 2 * t + par;           // row 9 only when t==4&&par==1 (guarded)
            odl[t] = row / 3;
            ohl[t] = row - odl[t] * 3;
        }

        v4f acc[5][4];
        #pragma unroll
        for (int t = 0; t < 5; ++t)
            #pragma unroll
            for (int nt = 0; nt < 4; ++nt)
                acc[t][nt] = (v4f){0.f, 0.f, 0.f, 0.f};

        const unsigned short* wcls = wt + O64[r] + l * K + q * 8;
        v8s bcur[4], bnxt[4];
        #pragma unroll
        for (int nt = 0; nt < 4; ++nt)
            bcur[nt] = *(const v8s*)(wcls + nt * 16 * K);

        int jd = 0, jh = 0, jw = 0;
        for (int s = 0; s < taps; ++s) {
            if (s + 1 < taps) {
                #pragma unroll
                for (int nt = 0; nt < 4; ++nt)
                    bnxt[nt] = *(const v8s*)(wcls + nt * 16 * K + (s + 1) * 32);
            }
            const int abase = laneA - jw * 8 - jd * 720 - jh * 144;
            #pragma unroll
            for (int t = 0; t < 5; ++t) {
                if (t < T) {
                    const v8s a = *(const v8s*)&xs[abase + odl[t] * 720 + ohl[t] * 144];
                    #pragma unroll
                    for (int nt = 0; nt < 4; ++nt)
                        acc[t][nt] = __builtin_amdgcn_mfma_f32_16x16x32_bf16(
                            a, bcur[nt], acc[t][nt], 0, 0, 0);
                }
            }
            if (++jw == nw) { jw = 0; if (++jh == nh) { jh = 0; ++jd; } }
            #pragma unroll
            for (int nt = 0; nt < 4; ++nt) bcur[nt] = bnxt[nt];
        }

        // fold acc into per-lane pool maxes: m(ow') = 4q+reg, wjl = m/3, skip m==15
        #pragma unroll
        for (int t = 0; t < 5; ++t) {
            if (t < T) {
                #pragma unroll
                for (int nt = 0; nt < 4; ++nt) {
                    #pragma unroll
                    for (int reg = 0; reg < 4; ++reg) {
                        int m = 4 * q + reg;
                        if (m < 15) {
                            int wjl = m / 3;
                            float v = acc[t][nt][reg];
                            if (wjl == wjA) pmax[nt][0] = fmaxf(pmax[nt][0], v);
                            else            pmax[nt][1] = fmaxf(pmax[nt][1], v);
                        }
                    }
                }
            }
        }
    }

    // ---- cross-wave reduction ----
    {
        int base = ((wv * 4 + q) * 16 + l) * 8;
        #pragma unroll
        for (int nt = 0; nt < 4; ++nt) {
            P[base + nt * 2 + 0] = pmax[nt][0];
            P[base + nt * 2 + 1] = pmax[nt][1];
        }
    }
    __syncthreads();

    static constexpr int wjAt[4] = {0, 1, 2, 4};
    static constexpr int wjBt[4] = {1, 2, 3, 5};
    for (int oi = threadIdx.x; oi < 320; oi += 256) {
        int co = oi / 5;
        int wjl = oi - co * 5;
        int lc = co & 15, ntc = co >> 4;
        float v = -INFINITY;
        #pragma unroll
        for (int w = 0; w < 4; ++w) {
            #pragma unroll
            for (int qq = 0; qq < 4; ++qq) {
                const float* pp = &P[((w * 4 + qq) * 16 + lc) * 8 + ntc * 2];
                if (wjAt[qq] == wjl) v = fmaxf(v, pp[0]);
                if (wjBt[qq] == wjl) v = fmaxf(v, pp[1]);
            }
        }
        Y[co * 5 + wjl] = v + bias[co];
    }
    __syncthreads();

    if (threadIdx.x < 5) {
        float s = 0.f;
        #pragma unroll
        for (int co = 0; co < 64; ++co) s += Y[co * 5 + threadIdx.x];
        out[((n * 5 + dj) * 10 + hj) * 10 + whalf * 5 + threadIdx.x] = s;
    }
}

extern "C" void kernel_launch(void* const* d_in, const int* in_sizes, int n_in,
                              void* d_out, int out_size, void* d_ws, size_t ws_size,
                              hipStream_t stream) {
    const float* x    = (const float*)d_in[0];   // (16,32,16,32,32)
    const float* w    = (const float*)d_in[1];   // (32,64,5,5,5)
    const float* bias = (const float*)d_in[2];   // (64,)
    float*       out  = (float*)d_out;           // 8000
    unsigned short* wt = (unsigned short*)d_ws;  // 256000 halves = 512 KB

    wprep<<<dim3(216, 8), 256, 0, stream>>>(w, wt);
    fused_main<<<dim3(1600), 256, 0, stream>>>(x, wt, bias, out);
}

// Round 3
// 264.371 us; speedup vs baseline: 8.1617x; 1.2548x over previous
//
#include <hip/hip_runtime.h>

typedef short v8s __attribute__((ext_vector_type(8)));
typedef float v4f __attribute__((ext_vector_type(4)));

#define N_  16
#define CI_ 32
#define CO_ 64
#define DI  16
#define HI  32
#define WI  32
#define NEGINF (-__builtin_inff())

__device__ __forceinline__ unsigned short f2bf(float f) {
    unsigned int u = __float_as_uint(f);
    unsigned int r = (u + 0x7FFFu + ((u >> 16) & 1u)) >> 16;
    return (unsigned short)r;
}

// async 16B global->LDS (dst = wave-uniform base + lane*16)
__device__ __forceinline__ void gld16(const void* g, void* l) {
    __builtin_amdgcn_global_load_lds(
        (const __attribute__((address_space(1))) void*)g,
        (__attribute__((address_space(3))) void*)l, 16, 0, 0);
}

// Build w_t[class][co][k] bf16, k = tap*32 + ci, tap = (jd*nh+jh)*nw+jw.
__global__ void wprep(const float* __restrict__ w, unsigned short* __restrict__ wt) {
    const int r = blockIdx.y;
    const int rd = r >> 2, rh = (r >> 1) & 1, rw = r & 1;
    const int nd = rd ? 2 : 3, nh = rh ? 2 : 3, nw = rw ? 2 : 3;
    const int K = nd * nh * nw * 32;
    static constexpr int O64[8] = {0, 55296, 92160, 129024, 153600, 190464, 215040, 239616};
    int t = blockIdx.x * 256 + threadIdx.x;
    if (t >= 64 * K) return;
    int co = t / K;
    int k  = t - co * K;
    int ci = k & 31;
    int tap = k >> 5;
    int jw = tap % nw;
    int jh = (tap / nw) % nh;
    int jd = tap / (nw * nh);
    int kd = rd + 2 * jd, kh = rh + 2 * jh, kw = rw + 2 * jw;
    wt[O64[r] + t] = f2bf(w[(ci * CO_ + co) * 125 + kd * 25 + kh * 5 + kw]);
}

// x -> bf16, pre-padded (low edges), layout [n][cg4][pd17][ph32][pw33][c8]
__global__ void xprep(const float* __restrict__ x, unsigned short* __restrict__ xp) {
    int t = blockIdx.x * 256 + threadIdx.x;
    if (t >= 16 * 4 * 17 * 32 * 33) return;   // 1,148,928
    int pw = t % 33;
    int q1 = t / 33;
    int ph = q1 & 31;
    int q2 = q1 >> 5;
    int pd = q2 % 17;
    int q3 = q2 / 17;
    int cg = q3 & 3;
    int n  = q3 >> 2;
    v8s o;
    if (pd == 0 || ph == 0 || pw == 0) {
        o = (v8s){0, 0, 0, 0, 0, 0, 0, 0};
    } else {
        const float* xb = x + ((((size_t)(n * 32 + cg * 8) * 16 + (pd - 1)) * 32
                                + (ph - 1)) * 32 + (pw - 1));
        #pragma unroll
        for (int c = 0; c < 8; ++c)
            o[c] = (short)f2bf(xb[(size_t)c * 16384]);   // 16*32*32 per-ci stride
    }
    *(v8s*)(xp + (size_t)t * 8) = o;
}

// per-class GEMM body; PAR = row parity of this wave. Folds pool-max into pmax.
template<bool PAR>
__device__ __forceinline__ void run_class(
        const unsigned short* __restrict__ xs,   // LDS patch
        int laneAB,                              // byte addr: q*7200 + (l+2)*16 + 3456
        const unsigned short* __restrict__ wcls, // wt + O64[r] + l*K + q*8
        const int K, const int taps, const int nw, const int nh,
        unsigned Bm, bool isQ3, float (&pmax)[4][2])
{
    constexpr int T  = PAR ? 4 : 5;
    constexpr int R0 = PAR ? 288 : 0;
    constexpr int R1 = PAR ? 1440 : 576;
    constexpr int R2 = PAR ? 2016 : 1728;
    constexpr int R3 = PAR ? 3168 : 2880;
    constexpr int R4 = 3456;

    const char* xb = (const char*)xs;

    v4f acc[T][4];
    #pragma unroll
    for (int t = 0; t < T; ++t)
        #pragma unroll
        for (int nt = 0; nt < 4; ++nt)
            acc[t][nt] = (v4f){0.f, 0.f, 0.f, 0.f};

    v8s B0[4], B1[4];
    #pragma unroll
    for (int nt = 0; nt < 4; ++nt) B0[nt] = *(const v8s*)(wcls + nt * 16 * K);

    int aoff = 0, jw = 0, jh = 0;
    auto adv = [&]() {
        aoff += 16; ++jw;
        if (jw == nw) { jw = 0; aoff += 288 - 16 * nw; ++jh;
            if (jh == nh) { jh = 0; aoff += 1440 - 288 * nh; } }
    };
    auto comp = [&](const v8s (&B)[4]) {
        const int va = laneAB - aoff;
        v8s a0 = *(const v8s*)(xb + va + R0);
        v8s a1 = *(const v8s*)(xb + va + R1);
        v8s a2 = *(const v8s*)(xb + va + R2);
        v8s a3 = *(const v8s*)(xb + va + R3);
        v8s a4;
        if (!PAR) a4 = *(const v8s*)(xb + va + R4);
        #pragma unroll
        for (int nt = 0; nt < 4; ++nt) {
            acc[0][nt] = __builtin_amdgcn_mfma_f32_16x16x32_bf16(a0, B[nt], acc[0][nt], 0, 0, 0);
            acc[1][nt] = __builtin_amdgcn_mfma_f32_16x16x32_bf16(a1, B[nt], acc[1][nt], 0, 0, 0);
            acc[2][nt] = __builtin_amdgcn_mfma_f32_16x16x32_bf16(a2, B[nt], acc[2][nt], 0, 0, 0);
            acc[3][nt] = __builtin_amdgcn_mfma_f32_16x16x32_bf16(a3, B[nt], acc[3][nt], 0, 0, 0);
            if (!PAR)
                acc[4][nt] = __builtin_amdgcn_mfma_f32_16x16x32_bf16(a4, B[nt], acc[4][nt], 0, 0, 0);
        }
    };

    int s = 0;
    while (s + 2 <= taps) {
        #pragma unroll
        for (int nt = 0; nt < 4; ++nt)
            B1[nt] = *(const v8s*)(wcls + (s + 1) * 32 + nt * 16 * K);
        comp(B0); adv();
        if (s + 2 < taps) {
            #pragma unroll
            for (int nt = 0; nt < 4; ++nt)
                B0[nt] = *(const v8s*)(wcls + (s + 2) * 32 + nt * 16 * K);
        }
        comp(B1); adv();
        s += 2;
    }
    if (s < taps) comp(B0);

    // fold: max over rows first, then branchless slot dispatch
    #pragma unroll
    for (int nt = 0; nt < 4; ++nt) {
        #pragma unroll
        for (int reg = 0; reg < 4; ++reg) {
            float v = acc[0][nt][reg];
            #pragma unroll
            for (int t = 1; t < T; ++t) v = fmaxf(v, acc[t][nt][reg]);
            if (reg == 3) v = isQ3 ? NEGINF : v;   // skip m==15
            const bool bB = (Bm >> reg) & 1u;
            pmax[nt][0] = fmaxf(pmax[nt][0], bB ? NEGINF : v);
            pmax[nt][1] = fmaxf(pmax[nt][1], bB ? v : NEGINF);
        }
    }
}

template<bool PRE>
__global__ __launch_bounds__(256, 3)
void fused_main(const float* __restrict__ x, const unsigned short* __restrict__ xp,
                const unsigned short* __restrict__ wt,
                const float* __restrict__ bias, float* __restrict__ out) {
    __shared__ __align__(16) unsigned short xs[14400];  // [g4][id'5][ih'5][iw'18][c8]
    __shared__ float P[2048];                           // [wave4][q4][l16][nt4][slot2]
    __shared__ float Y[320];                            // [co64][wjl5]

    const int b = blockIdx.x;
    const int whalf = b & 1;
    const int hj = (b >> 1) % 10;
    const int dj = (b / 20) % 5;
    const int n  = b / 100;

    if (PRE) {
        // DMA staging: 1800 chunks x 16B from pre-padded xp
        const int t  = threadIdx.x;
        const int wv_ = t >> 6;
        #pragma unroll
        for (int i = 0; i < 8; ++i) {
            int c = i * 256 + t;
            if (c < 1800) {
                int row = c / 18;
                int iwc = c - row * 18;
                int cg  = row / 25;
                int rr  = row - cg * 25;
                int idl = rr / 5;
                int ihl = rr - idl * 5;
                size_t goff = ((((size_t)((n * 4 + cg) * 17 + 3 * dj + idl)) * 32
                                + 3 * hj + ihl) * 33 + 15 * whalf + iwc) * 8;
                gld16(xp + goff, (char*)xs + i * 4096 + wv_ * 1024);
            }
        }
    } else {
        // fallback: stage from raw fp32 x (round-2 path)
        const int id0 = 3 * dj - 1, ih0 = 3 * hj - 1, iwb = 15 * whalf - 1;
        const float* xn = x + (size_t)n * (CI_ * DI * HI * WI);
        for (int e = threadIdx.x; e < 14400; e += 256) {
            int ci   = e / 450;
            int rem  = e - ci * 450;
            int idp  = rem / 90;
            int rem2 = rem - idp * 90;
            int ihp  = rem2 / 18;
            int iwp  = rem2 - ihp * 18;
            int id = id0 + idp, ih = ih0 + ihp, iw = iwb + iwp;
            float v = 0.f;
            if (id >= 0 && ih >= 0 && iw >= 0)
                v = xn[((ci * DI + id) * HI + ih) * WI + iw];
            xs[(ci >> 3) * 3600 + idp * 720 + ihp * 144 + iwp * 8 + (ci & 7)] = f2bf(v);
        }
    }
    __syncthreads();

    const int lane = threadIdx.x & 63;
    const int wv   = threadIdx.x >> 6;
    const int l = lane & 15, q = lane >> 4;
    const int wp2 = wv >> 1;   // class group
    const int wp  = wv & 1;    // row-parity split

    const int laneAB = q * 7200 + (l + 2) * 16 + 3456;  // bytes

    static constexpr int G0[4] = {0, 3, 5, 6}, G1[4] = {1, 2, 4, 7};
    static constexpr int tapsT[8] = {27, 18, 18, 12, 18, 12, 12, 8};
    static constexpr int KT[8]    = {864, 576, 576, 384, 576, 384, 384, 256};
    static constexpr int O64[8]   = {0, 55296, 92160, 129024, 153600, 190464, 215040, 239616};
    static constexpr int nwT[8]   = {3, 2, 3, 2, 3, 2, 3, 2};
    static constexpr int nhT[8]   = {3, 3, 2, 2, 3, 3, 2, 2};

    float pmax[4][2];
    #pragma unroll
    for (int nt = 0; nt < 4; ++nt) { pmax[nt][0] = NEGINF; pmax[nt][1] = NEGINF; }

    const unsigned Bm = (0x0EC8u >> (q << 2)) & 0xFu;
    const bool isQ3 = (q == 3);

    #pragma unroll 1
    for (int c4 = 0; c4 < 4; ++c4) {
        const int r = wp2 ? G1[c4] : G0[c4];
        const int taps = tapsT[r], K = KT[r], nw = nwT[r], nh = nhT[r];
        const unsigned short* wcls = wt + O64[r] + l * K + q * 8;
        if ((wp + c4) & 1)
            run_class<true >(xs, laneAB, wcls, K, taps, nw, nh, Bm, isQ3, pmax);
        else
            run_class<false>(xs, laneAB, wcls, K, taps, nw, nh, Bm, isQ3, pmax);
    }

    // ---- cross-wave reduction ----
    {
        int base = ((wv * 4 + q) * 16 + l) * 8;
        #pragma unroll
        for (int nt = 0; nt < 4; ++nt) {
            P[base + nt * 2 + 0] = pmax[nt][0];
            P[base + nt * 2 + 1] = pmax[nt][1];
        }
    }
    __syncthreads();

    static constexpr int wjAt[4] = {0, 1, 2, 4};
    static constexpr int wjBt[4] = {1, 2, 3, 5};
    for (int oi = threadIdx.x; oi < 320; oi += 256) {
        int co = oi / 5;
        int wjl = oi - co * 5;
        int lc = co & 15, ntc = co >> 4;
        float v = NEGINF;
        #pragma unroll
        for (int w = 0; w < 4; ++w) {
            #pragma unroll
            for (int qq = 0; qq < 4; ++qq) {
                const float* pp = &P[((w * 4 + qq) * 16 + lc) * 8 + ntc * 2];
                if (wjAt[qq] == wjl) v = fmaxf(v, pp[0]);
                if (wjBt[qq] == wjl) v = fmaxf(v, pp[1]);
            }
        }
        Y[co * 5 + wjl] = v + bias[co];
    }
    __syncthreads();

    if (threadIdx.x < 5) {
        float s = 0.f;
        #pragma unroll
        for (int co = 0; co < 64; ++co) s += Y[co * 5 + threadIdx.x];
        out[((n * 5 + dj) * 10 + hj) * 10 + whalf * 5 + threadIdx.x] = s;
    }
}

extern "C" void kernel_launch(void* const* d_in, const int* in_sizes, int n_in,
                              void* d_out, int out_size, void* d_ws, size_t ws_size,
                              hipStream_t stream) {
    const float* x    = (const float*)d_in[0];
    const float* w    = (const float*)d_in[1];
    const float* bias = (const float*)d_in[2];
    float*       out  = (float*)d_out;
    unsigned short* wt = (unsigned short*)d_ws;                        // 512000 B
    unsigned short* xp = (unsigned short*)((char*)d_ws + 512512);      // 18,382,848 B
    const size_t XP_NEED = 512512 + 18382848;

    wprep<<<dim3(216, 8), 256, 0, stream>>>(w, wt);
    if (ws_size >= XP_NEED) {
        xprep<<<dim3(4488), 256, 0, stream>>>(x, xp);
        fused_main<true><<<dim3(1600), 256, 0, stream>>>(x, xp, wt, bias, out);
    } else {
        fused_main<false><<<dim3(1600), 256, 0, stream>>>(x, xp, wt, bias, out);
    }
}